// Round 1
// baseline (64.469 us; speedup 1.0000x reference)
//
#include <hip/hip_runtime.h>
#include <math.h>

#define NB 4
#define NN 512
#define ND 128
#define NC 10
#define TILE 32
#define PAD 132  // 128 + 4 floats: row r starts at bank (4r)%32 -> 2-way max for stride-16 rows

__global__ __launch_bounds__(256) void w2ner_main(
    const float* __restrict__ x, const int* __restrict__ span,
    const int* __restrict__ seqlen, const float* __restrict__ Wm,
    const float* __restrict__ bias, float* __restrict__ out,
    float* __restrict__ accum)
{
    __shared__ float sXi[TILE * PAD];
    __shared__ float sXj[TILE * PAD];
    __shared__ float sW[NC * ND];   // transposed: sW[c*ND + d] = W[d*NC + c]
    __shared__ float sB[NC];
    __shared__ float sRed[4 * 5];

    const int tid = threadIdx.x;
    const int ntj = NN / TILE;                  // 16
    const int blk = blockIdx.x;
    const int b   = blk / (ntj * ntj);
    const int rem = blk % (ntj * ntj);
    const int i0  = (rem / ntj) * TILE;
    const int j0  = (rem % ntj) * TILE;

    const float* xb = x + (size_t)b * NN * ND;

    // stage x tiles (coalesced float4)
    for (int idx = tid; idx < TILE * (ND / 4); idx += 256) {
        int row = idx >> 5;            // 32 float4 per row
        int c4  = (idx & 31) << 2;
        float4 vi = *reinterpret_cast<const float4*>(xb + (i0 + row) * ND + c4);
        float4 vj = *reinterpret_cast<const float4*>(xb + (j0 + row) * ND + c4);
        *reinterpret_cast<float4*>(sXi + row * PAD + c4) = vi;
        *reinterpret_cast<float4*>(sXj + row * PAD + c4) = vj;
    }
    // stage W transposed [c][d]
    for (int idx = tid; idx < ND * NC; idx += 256) {
        int d = idx / NC, c = idx - d * NC;
        sW[c * ND + d] = Wm[idx];
    }
    if (tid < NC) sB[tid] = bias[tid];
    __syncthreads();

    const int ti = tid >> 4;   // 0..15 -> rows ti, ti+16
    const int tj = tid & 15;   // 0..15 -> cols tj, tj+16

    float acc[2][2][NC];
    #pragma unroll
    for (int p = 0; p < 2; ++p)
        #pragma unroll
        for (int q = 0; q < 2; ++q)
            #pragma unroll
            for (int c = 0; c < NC; ++c) acc[p][q][c] = 0.f;

    const float* pXi0 = sXi + ti * PAD;
    const float* pXi1 = sXi + (ti + 16) * PAD;
    const float* pXj0 = sXj + tj * PAD;
    const float* pXj1 = sXj + (tj + 16) * PAD;

    #pragma unroll 2
    for (int d4 = 0; d4 < ND; d4 += 4) {
        float4 af[2], bf[2];
        af[0] = *reinterpret_cast<const float4*>(pXi0 + d4);
        af[1] = *reinterpret_cast<const float4*>(pXi1 + d4);
        bf[0] = *reinterpret_cast<const float4*>(pXj0 + d4);
        bf[1] = *reinterpret_cast<const float4*>(pXj1 + d4);
        float4 w[NC];
        #pragma unroll
        for (int c = 0; c < NC; ++c)
            w[c] = *reinterpret_cast<const float4*>(sW + c * ND + d4);
        #pragma unroll
        for (int p = 0; p < 2; ++p) {
            #pragma unroll
            for (int q = 0; q < 2; ++q) {
                float4 pr;
                pr.x = af[p].x * bf[q].x;
                pr.y = af[p].y * bf[q].y;
                pr.z = af[p].z * bf[q].z;
                pr.w = af[p].w * bf[q].w;
                #pragma unroll
                for (int c = 0; c < NC; ++c)
                    acc[p][q][c] += pr.x * w[c].x + pr.y * w[c].y
                                  + pr.z * w[c].z + pr.w * w[c].w;
            }
        }
    }

    const int sl = seqlen[b];
    float lsum = 0.f, accn = 0.f, tpn = 0.f, tnn = 0.f, fpn = 0.f;

    #pragma unroll
    for (int p = 0; p < 2; ++p) {
        #pragma unroll
        for (int q = 0; q < 2; ++q) {
            const int i = i0 + ti + p * 16;
            const int j = j0 + tj + q * 16;
            float l[NC];
            #pragma unroll
            for (int c = 0; c < NC; ++c) l[c] = acc[p][q][c] + sB[c];
            // first-occurrence argmax (matches jnp.argmax)
            int am = 0; float mx = l[0];
            #pragma unroll
            for (int c = 1; c < NC; ++c) { if (l[c] > mx) { mx = l[c]; am = c; } }
            float s = 0.f;
            #pragma unroll
            for (int c = 0; c < NC; ++c) s += expf(l[c] - mx);
            const size_t off = (size_t)b * NN * NN + (size_t)i * NN + j;
            const int sp = span[off];
            // gather l[sp] without runtime array index (avoid scratch)
            float lsp = l[0];
            #pragma unroll
            for (int c = 1; c < NC; ++c) lsp = (sp == c) ? l[c] : lsp;
            const float lp   = (lsp - mx) - logf(s);   // log(prob)
            const float prob = expf(lp);
            const float om   = 1.f - prob;
            const float lm   = -(om * om) * lp;        // focal loss term
            const bool v = (i < sl) && (j < sl);
            const int pred = v ? am : 0;
            out[off] = (float)pred;
            if (v) { lsum += lm; if (pred == sp) accn += 1.f; }
            if (sp > 0) { if (pred == sp) tpn += 1.f; else tnn += 1.f; }
            else if (pred > 0 && v) fpn += 1.f;
        }
    }

    // block reduction: 5 partials
    float vals[5] = { lsum, accn, tpn, tnn, fpn };
    #pragma unroll
    for (int k = 0; k < 5; ++k) {
        float vv = vals[k];
        for (int o = 32; o > 0; o >>= 1) vv += __shfl_down(vv, o);
        vals[k] = vv;
    }
    const int wave = tid >> 6;
    const int lane = tid & 63;
    if (lane == 0) {
        #pragma unroll
        for (int k = 0; k < 5; ++k) sRed[wave * 5 + k] = vals[k];
    }
    __syncthreads();
    if (tid < 5) {
        float t = sRed[tid] + sRed[5 + tid] + sRed[10 + tid] + sRed[15 + tid];
        atomicAdd(&accum[tid], t);
    }
}

__global__ void w2ner_final(const int* __restrict__ seqlen,
                            const float* __restrict__ accum,
                            float* __restrict__ out)
{
    if (threadIdx.x == 0 && blockIdx.x == 0) {
        float s2 = 0.f;
        for (int k = 0; k < NB; ++k) { float s = (float)seqlen[k]; s2 += s * s; }
        const size_t base = (size_t)NB * NN * NN;
        out[base + 0] = accum[2];            // tp
        out[base + 1] = accum[3];            // tn
        out[base + 2] = accum[4];            // fp
        out[base + 3] = accum[0] / s2;       // loss
        out[base + 4] = accum[1] / s2;       // accuracy
    }
}

extern "C" void kernel_launch(void* const* d_in, const int* in_sizes, int n_in,
                              void* d_out, int out_size, void* d_ws, size_t ws_size,
                              hipStream_t stream) {
    const float* x      = (const float*)d_in[0];
    const int*   span   = (const int*)d_in[1];
    const int*   seqlen = (const int*)d_in[2];
    const float* Wm     = (const float*)d_in[3];
    const float* bias   = (const float*)d_in[4];
    float* out   = (float*)d_out;
    float* accum = (float*)d_ws;

    hipMemsetAsync(accum, 0, 5 * sizeof(float), stream);
    const int ntiles = NN / TILE;                      // 16
    dim3 grid(NB * ntiles * ntiles);                   // 1024 blocks
    w2ner_main<<<grid, 256, 0, stream>>>(x, span, seqlen, Wm, bias, out, accum);
    w2ner_final<<<1, 64, 0, stream>>>(seqlen, accum, out);
}